// Round 1
// baseline (37126.669 us; speedup 1.0000x reference)
//
#include <hip/hip_runtime.h>
#include <cmath>

#define T_STEPS 8192
#define XD 1024
#define HD 2048
#define YD 1024
#define NBLK 64

// ---------------------------------------------------------------------------
// Generic f32 GEMM: C[M][N] = A[M][K] @ B[K][N] + bias[N]
// 128x128 block tile, BK=16, 256 threads, 8x8 micro-tile per thread.
// ---------------------------------------------------------------------------
#define BM 128
#define BN 128
#define BK 16

__global__ __launch_bounds__(256)
void gemm_bias_f32(const float* __restrict__ A, const float* __restrict__ B,
                   const float* __restrict__ bias, float* __restrict__ C,
                   int M, int N, int K)
{
    __shared__ float As[BK][BM + 4];   // +4 pad: breaks write conflicts, keeps 16B align
    __shared__ float Bs[BK][BN + 4];
    const int tid = threadIdx.x;
    const int bm = blockIdx.y * BM;
    const int bn = blockIdx.x * BN;
    const int tx = tid & 15;
    const int ty = tid >> 4;

    float acc[8][8];
    #pragma unroll
    for (int i = 0; i < 8; ++i)
        #pragma unroll
        for (int j = 0; j < 8; ++j) acc[i][j] = 0.f;

    for (int k0 = 0; k0 < K; k0 += BK) {
        // global loads into regs (A: 128x16, B: 16x128; 2 float4 each per thread)
        const int arow = tid >> 2;            // 0..63
        const int akq  = (tid & 3) * 4;       // 0,4,8,12
        float4 a0 = *reinterpret_cast<const float4*>(&A[(size_t)(bm + arow) * K + k0 + akq]);
        float4 a1 = *reinterpret_cast<const float4*>(&A[(size_t)(bm + 64 + arow) * K + k0 + akq]);
        const int brow = tid >> 5;            // 0..7
        const int bcol = (tid & 31) * 4;      // 0..124
        float4 b0 = *reinterpret_cast<const float4*>(&B[(size_t)(k0 + brow) * N + bn + bcol]);
        float4 b1 = *reinterpret_cast<const float4*>(&B[(size_t)(k0 + 8 + brow) * N + bn + bcol]);

        __syncthreads();   // previous iter's LDS reads done before overwrite
        As[akq + 0][arow] = a0.x; As[akq + 1][arow] = a0.y;
        As[akq + 2][arow] = a0.z; As[akq + 3][arow] = a0.w;
        As[akq + 0][arow + 64] = a1.x; As[akq + 1][arow + 64] = a1.y;
        As[akq + 2][arow + 64] = a1.z; As[akq + 3][arow + 64] = a1.w;
        *reinterpret_cast<float4*>(&Bs[brow][bcol])     = b0;
        *reinterpret_cast<float4*>(&Bs[brow + 8][bcol]) = b1;
        __syncthreads();

        #pragma unroll
        for (int kk = 0; kk < BK; ++kk) {
            float af[8], bf[8];
            *reinterpret_cast<float4*>(&af[0]) = *reinterpret_cast<const float4*>(&As[kk][ty * 8]);
            *reinterpret_cast<float4*>(&af[4]) = *reinterpret_cast<const float4*>(&As[kk][ty * 8 + 4]);
            *reinterpret_cast<float4*>(&bf[0]) = *reinterpret_cast<const float4*>(&Bs[kk][tx * 8]);
            *reinterpret_cast<float4*>(&bf[4]) = *reinterpret_cast<const float4*>(&Bs[kk][tx * 8 + 4]);
            #pragma unroll
            for (int i = 0; i < 8; ++i)
                #pragma unroll
                for (int j = 0; j < 8; ++j)
                    acc[i][j] = fmaf(af[i], bf[j], acc[i][j]);
        }
    }

    #pragma unroll
    for (int i = 0; i < 8; ++i) {
        const int row = bm + ty * 8 + i;
        #pragma unroll
        for (int jq = 0; jq < 2; ++jq) {
            const int col = bn + tx * 8 + jq * 4;
            float4 o;
            o.x = acc[i][jq * 4 + 0] + bias[col + 0];
            o.y = acc[i][jq * 4 + 1] + bias[col + 1];
            o.z = acc[i][jq * 4 + 2] + bias[col + 2];
            o.w = acc[i][jq * 4 + 3] + bias[col + 3];
            *reinterpret_cast<float4*>(&C[(size_t)row * N + col]) = o;
        }
    }
}

// ---------------------------------------------------------------------------
// Recurrence: 64 persistent blocks, Wh_h held in VGPRs (f32, 16MB across 64 CUs).
// Block b owns output columns [b*32, b*32+32). Wave w owns 4 of them; lane
// covers 32 input rows. Per-step all-to-all h exchange through LLC via
// device-scope atomics + per-step arrival counter.
// ---------------------------------------------------------------------------
__device__ __forceinline__ int swz_chunk(int c) { return c ^ ((c >> 3) & 7); }

__global__ __launch_bounds__(512)
void rnn_recur(const float* __restrict__ Whh, const float* __restrict__ h0,
               float* __restrict__ buf /* [T][HD]: in xW+bh, out h */,
               int* __restrict__ cnt /* [T], zeroed */)
{
    const int b    = blockIdx.x;       // 0..63
    const int tid  = threadIdx.x;      // 0..511
    const int wave = tid >> 6;         // 0..7
    const int lane = tid & 63;
    const int jbase = b * 32 + wave * 4;

    // ---- persistent weights: w[k][oo] = Whh[lane*32+k][jbase+oo] (128 VGPRs)
    float w[32][4];
    #pragma unroll
    for (int k = 0; k < 32; ++k) {
        float4 v = *reinterpret_cast<const float4*>(&Whh[(size_t)(lane * 32 + k) * HD + jbase]);
        w[k][0] = v.x; w[k][1] = v.y; w[k][2] = v.z; w[k][3] = v.w;
    }

    __shared__ float hl[HD];   // swizzled h buffer (8KB)
    {
        float4 v;
        v.x = h0[tid * 4 + 0]; v.y = h0[tid * 4 + 1];
        v.z = h0[tid * 4 + 2]; v.w = h0[tid * 4 + 3];
        reinterpret_cast<float4*>(hl)[swz_chunk(tid)] = v;
    }
    __syncthreads();

    for (int t = 0; t < T_STEPS; ++t) {
        // ---- partial dots: 4 outputs x 32 inputs per lane, h from LDS
        float acc0 = 0.f, acc1 = 0.f, acc2 = 0.f, acc3 = 0.f;
        #pragma unroll
        for (int c8 = 0; c8 < 8; ++c8) {
            float4 f = reinterpret_cast<float4*>(hl)[swz_chunk(lane * 8 + c8)];
            float fv[4] = {f.x, f.y, f.z, f.w};
            #pragma unroll
            for (int m = 0; m < 4; ++m) {
                acc0 = fmaf(w[c8 * 4 + m][0], fv[m], acc0);
                acc1 = fmaf(w[c8 * 4 + m][1], fv[m], acc1);
                acc2 = fmaf(w[c8 * 4 + m][2], fv[m], acc2);
                acc3 = fmaf(w[c8 * 4 + m][3], fv[m], acc3);
            }
        }
        // ---- full-wave butterfly reduce (all 64 lanes -> total dot)
        #pragma unroll
        for (int off = 32; off; off >>= 1) {
            acc0 += __shfl_xor(acc0, off);
            acc1 += __shfl_xor(acc1, off);
            acc2 += __shfl_xor(acc2, off);
            acc3 += __shfl_xor(acc3, off);
        }
        // ---- lanes 0..3 finalize their output column
        if (lane < 4) {
            float a = (lane == 0) ? acc0 : (lane == 1) ? acc1 : (lane == 2) ? acc2 : acc3;
            const size_t idx = (size_t)t * HD + jbase + lane;
            a += buf[idx];                 // xW[t][j] + bh[j] (owner-only slot)
            float hv = tanhf(a);
            __hip_atomic_store(&buf[idx], hv, __ATOMIC_RELAXED, __HIP_MEMORY_SCOPE_AGENT);
        }
        __syncthreads();                   // drains vmcnt: slice globally visible
        if (tid == 0)
            __hip_atomic_fetch_add(&cnt[t], 1, __ATOMIC_RELEASE, __HIP_MEMORY_SCOPE_AGENT);

        if (t + 1 < T_STEPS) {
            if (tid == 0) {
                while (__hip_atomic_load(&cnt[t], __ATOMIC_RELAXED, __HIP_MEMORY_SCOPE_AGENT) < NBLK) {}
            }
            __syncthreads();
            // gather full h_t (coherent loads bypass stale L2) into swizzled LDS
            const float* src = &buf[(size_t)t * HD];
            float4 v;
            v.x = __hip_atomic_load(&src[tid * 4 + 0], __ATOMIC_RELAXED, __HIP_MEMORY_SCOPE_AGENT);
            v.y = __hip_atomic_load(&src[tid * 4 + 1], __ATOMIC_RELAXED, __HIP_MEMORY_SCOPE_AGENT);
            v.z = __hip_atomic_load(&src[tid * 4 + 2], __ATOMIC_RELAXED, __HIP_MEMORY_SCOPE_AGENT);
            v.w = __hip_atomic_load(&src[tid * 4 + 3], __ATOMIC_RELAXED, __HIP_MEMORY_SCOPE_AGENT);
            reinterpret_cast<float4*>(hl)[swz_chunk(tid)] = v;
            __syncthreads();
        }
    }
}

// ---------------------------------------------------------------------------
__global__ void copy_tail(const float* __restrict__ buf, float* __restrict__ out)
{
    int i = blockIdx.x * blockDim.x + threadIdx.x;   // 0..2047
    if (i < HD)
        out[(size_t)T_STEPS * YD + i] = buf[(size_t)(T_STEPS - 1) * HD + i];
}

// ---------------------------------------------------------------------------
extern "C" void kernel_launch(void* const* d_in, const int* in_sizes, int n_in,
                              void* d_out, int out_size, void* d_ws, size_t ws_size,
                              hipStream_t stream)
{
    const float* x   = (const float*)d_in[0];   // [1][8192][1024]
    const float* h0  = (const float*)d_in[1];   // [2048]
    const float* WxX = (const float*)d_in[2];   // [1024][2048]
    const float* Whh = (const float*)d_in[3];   // [2048][2048]
    const float* Why = (const float*)d_in[4];   // [2048][1024]
    const float* bh  = (const float*)d_in[5];   // [2048]
    const float* by  = (const float*)d_in[6];   // [1024]
    float* out = (float*)d_out;                 // [8192*1024 + 2048]

    float* buf = (float*)d_ws;                                      // 64 MiB: xW -> H
    int*   cnt = (int*)((char*)d_ws + (size_t)T_STEPS * HD * sizeof(float));  // 32 KiB

    hipMemsetAsync(cnt, 0, T_STEPS * sizeof(int), stream);

    // Phase A: buf = x @ WxX + bh     (M=8192, K=1024, N=2048)
    dim3 gA(HD / BN, T_STEPS / BM);
    gemm_bias_f32<<<gA, 256, 0, stream>>>(x, WxX, bh, buf, T_STEPS, HD, XD);

    // Phase B: serial recurrence, records all h_t into buf
    rnn_recur<<<NBLK, 512, 0, stream>>>(Whh, h0, buf, cnt);

    // Phase C: out = H @ Why + by     (M=8192, K=2048, N=1024)
    dim3 gC(YD / BN, T_STEPS / BM);
    gemm_bias_f32<<<gC, 256, 0, stream>>>(buf, Why, by, out, T_STEPS, YD, HD);

    // h_final
    copy_tail<<<HD / 256, 256, 0, stream>>>(buf, out);
}